// Round 3
// baseline (195079.858 us; speedup 1.0000x reference)
//
#include <hip/hip_runtime.h>
#include <stdint.h>

#define BB 64
#define TT 2048
#define EE 256
#define HH 512
#define SLICE 128
#define HXN (BB * 2 * HH)   // u64 slots for h exchange

typedef unsigned long long u64;
typedef float f32x4 __attribute__((ext_vector_type(4)));

__device__ __forceinline__ u64 pack_vt(float v, unsigned tag) {
    return ((u64)tag << 32) | (u64)__float_as_uint(v);
}
// plain store: lands in the XCD's write-back L2 (visible to same-XCD sc0 loads)
__device__ __forceinline__ void st_l2(u64* p, u64 v) {
    asm volatile("global_store_dwordx2 %0, %1, off" :: "v"((u64)p), "v"(v) : "memory");
}
// L1-bypassing load: re-reads shared L2 every call
__device__ __forceinline__ u64 ld_l2(const u64* p) {
    u64 v;
    asm volatile("global_load_dwordx2 %0, %1, off sc0\n\ts_waitcnt vmcnt(0)"
                 : "=v"(v) : "v"((u64)p) : "memory");
    return v;
}

// 256 blocks (4/batch) x 512 threads. Block s owns h-rows [128s,128s+128).
// Thread (rg=tid>>4, kg=tid&15) owns 4 rows x 32-k-slice of W_hh and
// 4 rows x 16-e-slice of W_ih: 192 pinned VGPRs of weights.
// Per step: 12 ds_read_b128 + 192 fmaf -> 16-lane shfl reduce -> tanh on
// kg<4 lanes -> publish via L2 (fast) or agent atomics (fallback).
__global__ __launch_bounds__(512, 2)
void rnn_scan(const float* __restrict__ x,
              const int* __restrict__ lengths,
              const float* __restrict__ W_ih,
              const float* __restrict__ W_hh,
              const float* __restrict__ b_ih,
              const float* __restrict__ b_hh,
              const float* __restrict__ w_fc,
              const float* __restrict__ b_fc,
              float* __restrict__ out,   // [64] counts ++ [64][512] h_n
              u64* __restrict__ hx)      // [HXN] exchange ++ [512] handshake
{
    const int b   = blockIdx.x & 63;
    const int s   = blockIdx.x >> 6;
    const int tid = threadIdx.x;
    const int rg  = tid >> 4;      // 0..31  (4 rows each)
    const int kg  = tid & 15;      // 0..15  (32-wide k slice)
    const int row0 = s * SLICE + rg * 4;

    __shared__ float lds_h[2][HH];
    __shared__ float lds_x[2][EE];
    __shared__ int   sh_fast;

    // ---- weights into registers, pinned so they cannot be rematerialized ----
    f32x4 whh[4][8];
#pragma unroll
    for (int j = 0; j < 4; ++j)
#pragma unroll
        for (int i = 0; i < 8; ++i) {
            whh[j][i] = *(const f32x4*)&W_hh[(size_t)(row0 + j) * HH + kg * 32 + i * 4];
            asm volatile("" : "+v"(whh[j][i]));
        }
    f32x4 wih[4][4];
#pragma unroll
    for (int j = 0; j < 4; ++j)
#pragma unroll
        for (int i = 0; i < 4; ++i) {
            wih[j][i] = *(const f32x4*)&W_ih[(size_t)(row0 + j) * EE + kg * 16 + i * 4];
            asm volatile("" : "+v"(wih[j][i]));
        }
    const int   prow  = row0 + (kg & 3);
    const float bsumv = b_ih[prow] + b_hh[prow];

    f32x4 wf0 = {0.f, 0.f, 0.f, 0.f}, wf1 = wf0;
    float bfc = 0.f;
    if (s == 0 && tid < 64) {
        wf0 = *(const f32x4*)&w_fc[tid * 8];
        wf1 = *(const f32x4*)&w_fc[tid * 8 + 4];
        bfc = b_fc[0];
    }

    // ---- handshake: probe same-XCD L2 exchange, agree via agent atomics ----
    u64* hxb = hx + (size_t)b * 2 * HH;   // [2][512] parity slots for this batch
    if (tid == 0) {
        u64* iA = hx + HXN + (size_t)b * 4;
        u64* iB = hx + HXN + 256 + (size_t)b * 4;
        st_l2(&iA[s], pack_vt(0.f, 0xB100u + (unsigned)s));
        int ok = 1;
        for (int q = 0; q < 4; ++q) {
            const unsigned want = 0xB100u + (unsigned)q;
            int g = 0; u64 v;
            do { v = ld_l2(&iA[q]); } while ((unsigned)(v >> 32) != want && ++g < (1 << 13));
            if ((unsigned)(v >> 32) != want) { ok = 0; break; }
        }
        __hip_atomic_store(&iB[s], pack_vt(0.f, 0xC200u + (unsigned)(ok ? 1 : 0)),
                           __ATOMIC_RELAXED, __HIP_MEMORY_SCOPE_AGENT);
        int fastf = 1;
        for (int q = 0; q < 4; ++q) {
            int g = 0; unsigned got;
            do {
                u64 v = __hip_atomic_load(&iB[q], __ATOMIC_RELAXED, __HIP_MEMORY_SCOPE_AGENT);
                got = (unsigned)(v >> 32);
            } while ((got & ~1u) != 0xC200u && ++g < (1 << 22));
            if (got != 0xC201u) fastf = 0;
        }
        sh_fast = fastf;
    }

    const int len = lengths[b];
    const float* xrow = x + (size_t)b * TT * EE;

    // init: h0 = 0 in buf0, stage x[0]
    lds_h[0][tid] = 0.f;
    if (tid < EE) lds_x[0][tid] = xrow[tid];
    __syncthreads();
    const bool fastp = (sh_fast != 0);

    int count = 0;

#pragma unroll 1
    for (int t = 0; t < len; ++t) {
        const int p = t & 1;
        // x[t+1] prefetch: stager threads (tid>=384), 2 floats each
        const int si = tid - 384;
        float2 xn = make_float2(0.f, 0.f);
        if (si >= 0 && t + 1 < TT)
            xn = *(const float2*)&xrow[(size_t)(t + 1) * EE + si * 2];

        // ---- register-blocked GEMV slice: 4 rows x (32 hk + 16 xe) ----
        const f32x4* hk = (const f32x4*)&lds_h[p][kg * 32];
        const f32x4* xk = (const f32x4*)&lds_x[p][kg * 16];
        f32x4 a0 = {0.f,0.f,0.f,0.f}, a1 = a0, a2 = a0, a3 = a0;
#define FMA4(acc, w, v) \
        acc[0] = fmaf((w)[0], (v)[0], acc[0]); acc[1] = fmaf((w)[1], (v)[1], acc[1]); \
        acc[2] = fmaf((w)[2], (v)[2], acc[2]); acc[3] = fmaf((w)[3], (v)[3], acc[3]);
#pragma unroll
        for (int i = 0; i < 8; ++i) {
            f32x4 hv = hk[i];
            FMA4(a0, whh[0][i], hv) FMA4(a1, whh[1][i], hv)
            FMA4(a2, whh[2][i], hv) FMA4(a3, whh[3][i], hv)
        }
#pragma unroll
        for (int i = 0; i < 4; ++i) {
            f32x4 xv = xk[i];
            FMA4(a0, wih[0][i], xv) FMA4(a1, wih[1][i], xv)
            FMA4(a2, wih[2][i], xv) FMA4(a3, wih[3][i], xv)
        }
        float r0 = (a0[0] + a0[1]) + (a0[2] + a0[3]);
        float r1 = (a1[0] + a1[1]) + (a1[2] + a1[3]);
        float r2 = (a2[0] + a2[1]) + (a2[2] + a2[3]);
        float r3 = (a3[0] + a3[1]) + (a3[2] + a3[3]);
#pragma unroll
        for (int m = 1; m < 16; m <<= 1) {
            r0 += __shfl_xor(r0, m); r1 += __shfl_xor(r1, m);
            r2 += __shfl_xor(r2, m); r3 += __shfl_xor(r3, m);
        }
        const int jsel = kg & 3;
        float rsel = jsel == 0 ? r0 : (jsel == 1 ? r1 : (jsel == 2 ? r2 : r3));
        const float hval = tanhf(rsel + bsumv);

        const unsigned tag = (unsigned)(t + 1);
        u64* slot = hxb + (size_t)p * HH;

        if (kg < 4) {   // producer lanes: 128 h values per block
            const int gi = row0 + kg;
            lds_h[p ^ 1][gi] = hval;
            if (fastp) st_l2(&slot[gi], pack_vt(hval, tag));
            else __hip_atomic_store(&slot[gi], pack_vt(hval, tag),
                                    __ATOMIC_RELAXED, __HIP_MEMORY_SCOPE_AGENT);
        }

        if (tid < 384) {   // pollers: 3 remote slices, 1 value each
            const int sp = (s + 1 + (tid >> 7)) & 3;
            const int gi = sp * SLICE + (tid & 127);
            u64 v = 0;
            if (fastp) {
                int g = 0;
                do { v = ld_l2(&slot[gi]); } while ((unsigned)(v >> 32) != tag && ++g < (1 << 12));
            }
            if (!fastp || (unsigned)(v >> 32) != tag) {   // robust fallback
                int g = 0;
                do { v = __hip_atomic_load(&slot[gi], __ATOMIC_RELAXED,
                                           __HIP_MEMORY_SCOPE_AGENT);
                } while ((unsigned)(v >> 32) != tag && ++g < (1 << 22));
            }
            lds_h[p ^ 1][gi] = __uint_as_float((unsigned)v);
        } else if (t + 1 < TT) {   // stagers: write prefetched x row
            *(float2*)&lds_x[p ^ 1][si * 2] = xn;
        }
        __syncthreads();   // h_t complete in lds_h[p^1]

        if (s == 0) {
            if (tid < 64) {   // fc logit count, wave 0
                const f32x4* h4 = (const f32x4*)lds_h[p ^ 1];
                f32x4 v0 = h4[tid * 2], v1 = h4[tid * 2 + 1];
                float pd = v0[0]*wf0[0] + v0[1]*wf0[1] + v0[2]*wf0[2] + v0[3]*wf0[3]
                         + v1[0]*wf1[0] + v1[1]*wf1[1] + v1[2]*wf1[2] + v1[3]*wf1[3];
#pragma unroll
                for (int m = 1; m < 64; m <<= 1) pd += __shfl_xor(pd, m);
                if (tid == 0 && (pd + bfc) > 0.f) count++;
            }
            if (t == len - 1) out[64 + b * HH + tid] = lds_h[p ^ 1][tid];
        }
    }

    if (s == 0 && tid == 0) out[b] = (float)count;
}

extern "C" void kernel_launch(void* const* d_in, const int* in_sizes, int n_in,
                              void* d_out, int out_size, void* d_ws, size_t ws_size,
                              hipStream_t stream) {
    const float* x       = (const float*)d_in[0];
    const int*   lengths = (const int*)  d_in[1];
    const float* W_ih    = (const float*)d_in[2];
    const float* W_hh    = (const float*)d_in[3];
    const float* b_ih    = (const float*)d_in[4];
    const float* b_hh    = (const float*)d_in[5];
    const float* w_fc    = (const float*)d_in[6];
    const float* b_fc    = (const float*)d_in[7];
    float* out = (float*)d_out;
    u64*   hx  = (u64*)d_ws;   // 512KB exchange + 4KB handshake

    hipLaunchKernelGGL(rnn_scan, dim3(BB * 4), dim3(512), 0, stream,
                       x, lengths, W_ih, W_hh, b_ih, b_hh, w_fc, b_fc, out, hx);
}